// Round 1
// baseline (290.476 us; speedup 1.0000x reference)
//
#include <hip/hip_runtime.h>
#include <hip/hip_bf16.h>
#include <math.h>

#define DIM 64
#define GNUM 256
#define CNUM 10

// bf16x2 pack/unpack (RNE). All intermediates (h, layer outputs) are bf16 for
// traffic; alpha/softmax math stays f32 (as_/ad_ from f32 accumulators).
__device__ __forceinline__ unsigned bfpack(float a, float b) {
    unsigned ua = __builtin_bit_cast(unsigned, a);
    unsigned ub = __builtin_bit_cast(unsigned, b);
    ua += 0x7fffu + ((ua >> 16) & 1u);
    ub += 0x7fffu + ((ub >> 16) & 1u);
    return (ua >> 16) | (ub & 0xffff0000u);
}
__device__ __forceinline__ float bflo(unsigned u) { return __builtin_bit_cast(float, u << 16); }
__device__ __forceinline__ float bfhi(unsigned u) { return __builtin_bit_cast(float, u & 0xffff0000u); }
__device__ __forceinline__ float bfs(unsigned short u) { return __builtin_bit_cast(float, (unsigned)u << 16); }

// ---------------- CSR build ----------------
__global__ void deg_rank_kernel(const int* __restrict__ ei, int E, int N,
                                int* __restrict__ deg, int* __restrict__ rank) {
    int i = blockIdx.x * blockDim.x + threadIdx.x;
    int EP = E + N;
    if (i >= EP) return;
    int d = (i < E) ? ei[E + i] : (i - E);   // row 1 of edge_index = dst; self loops appended
    rank[i] = atomicAdd(&deg[d], 1);
}

// scan_blocks + graph_bounds, role-split by blockIdx.
__global__ __launch_bounds__(256) void scan_misc(const int* __restrict__ deg, int* __restrict__ part, int n, int nb,
                                                 const int* __restrict__ batch, int N,
                                                 int* __restrict__ gstart) {
    int bid = blockIdx.x;
    if (bid < nb) {
        __shared__ int ws[4];
        int i = bid * 256 + threadIdx.x;
        int v = (i < n) ? deg[i] : 0;
        #pragma unroll
        for (int d = 32; d >= 1; d >>= 1) v += __shfl_xor(v, d);
        if ((threadIdx.x & 63) == 0) ws[threadIdx.x >> 6] = v;
        __syncthreads();
        if (threadIdx.x == 0) part[bid] = ws[0] + ws[1] + ws[2] + ws[3];
    } else {
        for (int g = threadIdx.x; g <= GNUM; g += 256) {
            int lo = 0, hi = N;
            while (lo < hi) { int mid = (lo + hi) >> 1; if (batch[mid] < g) lo = mid + 1; else hi = mid; }
            gstart[g] = lo;
        }
    }
}

// scan_down with the top-level scan fused (nb <= 256 for N <= 65536).
__global__ __launch_bounds__(256) void scan_down(const int* __restrict__ deg, const int* __restrict__ part,
                                                 int* __restrict__ offs, int n) {
    __shared__ int ws[4];
    __shared__ int base_s;
    int tid = threadIdx.x, lane = tid & 63, wid = tid >> 6;
    int pv = (tid < (int)blockIdx.x) ? part[tid] : 0;
    #pragma unroll
    for (int d = 32; d >= 1; d >>= 1) pv += __shfl_xor(pv, d);
    if (lane == 0) ws[wid] = pv;
    __syncthreads();
    if (tid == 0) base_s = ws[0] + ws[1] + ws[2] + ws[3];
    __syncthreads();
    int i = blockIdx.x * 256 + tid;
    int v = (i < n) ? deg[i] : 0;
    int x = v;
    #pragma unroll
    for (int d = 1; d < 64; d <<= 1) { int t = __shfl_up(x, d); if (lane >= d) x += t; }
    if (lane == 63) ws[wid] = x;
    __syncthreads();
    int add = base_s;
    for (int w = 0; w < wid; ++w) add += ws[w];
    if (i < n) offs[i] = add + x - v;
    if (i == n - 1) offs[n] = add + x;
}

// ---------------- tiled mm body ----------------
// 64x64 tile per block; x transposed into LDS (stride 68 floats). 4x4 register
// tile per thread. Input either f32 (layer 1) or packed bf16 (layers 2,3);
// h output always packed bf16 (R7: halves dominant gather traffic).
#define XSTR 68
template<bool BF16IN>
__device__ __forceinline__ void mm_tile_body(int bid,
                                             const void* __restrict__ in_, const float* __restrict__ W,
                                             const float* __restrict__ a_s, const float* __restrict__ a_d,
                                             unsigned* __restrict__ hb, float* __restrict__ as_,
                                             float* __restrict__ ad_, int N) {
    __shared__ float Ws[DIM * DIM];
    __shared__ float xT[XSTR * DIM];
    int tid = threadIdx.x;
    int base = bid * 64;

    const float4* W4 = (const float4*)W;
    float4* Ws4 = (float4*)Ws;
    #pragma unroll
    for (int i = 0; i < 4; ++i) Ws4[tid + 256 * i] = W4[tid + 256 * i];

    {
        int row = tid >> 2;
        int kb = (tid & 3) << 4;
        int grow = base + row;
        int crow = grow < N ? grow : N - 1;
        if (BF16IN) {
            const unsigned* xr = (const unsigned*)in_ + ((size_t)crow << 5) + (kb >> 1);
            uint4 u0 = *(const uint4*)xr;
            uint4 u1 = *(const uint4*)(xr + 4);
            xT[(kb + 0) * XSTR + row] = bflo(u0.x);  xT[(kb + 1) * XSTR + row] = bfhi(u0.x);
            xT[(kb + 2) * XSTR + row] = bflo(u0.y);  xT[(kb + 3) * XSTR + row] = bfhi(u0.y);
            xT[(kb + 4) * XSTR + row] = bflo(u0.z);  xT[(kb + 5) * XSTR + row] = bfhi(u0.z);
            xT[(kb + 6) * XSTR + row] = bflo(u0.w);  xT[(kb + 7) * XSTR + row] = bfhi(u0.w);
            xT[(kb + 8) * XSTR + row] = bflo(u1.x);  xT[(kb + 9) * XSTR + row] = bfhi(u1.x);
            xT[(kb + 10) * XSTR + row] = bflo(u1.y); xT[(kb + 11) * XSTR + row] = bfhi(u1.y);
            xT[(kb + 12) * XSTR + row] = bflo(u1.z); xT[(kb + 13) * XSTR + row] = bfhi(u1.z);
            xT[(kb + 14) * XSTR + row] = bflo(u1.w); xT[(kb + 15) * XSTR + row] = bfhi(u1.w);
        } else {
            const float4* xr = (const float4*)((const float*)in_ + ((size_t)crow << 6) + kb);
            float4 v0 = xr[0], v1 = xr[1], v2 = xr[2], v3 = xr[3];
            xT[(kb + 0) * XSTR + row] = v0.x;  xT[(kb + 1) * XSTR + row] = v0.y;
            xT[(kb + 2) * XSTR + row] = v0.z;  xT[(kb + 3) * XSTR + row] = v0.w;
            xT[(kb + 4) * XSTR + row] = v1.x;  xT[(kb + 5) * XSTR + row] = v1.y;
            xT[(kb + 6) * XSTR + row] = v1.z;  xT[(kb + 7) * XSTR + row] = v1.w;
            xT[(kb + 8) * XSTR + row] = v2.x;  xT[(kb + 9) * XSTR + row] = v2.y;
            xT[(kb + 10) * XSTR + row] = v2.z; xT[(kb + 11) * XSTR + row] = v2.w;
            xT[(kb + 12) * XSTR + row] = v3.x; xT[(kb + 13) * XSTR + row] = v3.y;
            xT[(kb + 14) * XSTR + row] = v3.z; xT[(kb + 15) * XSTR + row] = v3.w;
        }
    }
    __syncthreads();

    int tx = tid & 15, ty = tid >> 4;
    int c0 = tx << 2, r0 = ty << 2;
    float acc[4][4] = {{0.f}};
    #pragma unroll 8
    for (int k = 0; k < DIM; ++k) {
        float4 xv = *(const float4*)(xT + k * XSTR + r0);
        float4 wv = *(const float4*)(Ws + k * DIM + c0);
        acc[0][0] += xv.x * wv.x; acc[0][1] += xv.x * wv.y; acc[0][2] += xv.x * wv.z; acc[0][3] += xv.x * wv.w;
        acc[1][0] += xv.y * wv.x; acc[1][1] += xv.y * wv.y; acc[1][2] += xv.y * wv.z; acc[1][3] += xv.y * wv.w;
        acc[2][0] += xv.z * wv.x; acc[2][1] += xv.z * wv.y; acc[2][2] += xv.z * wv.z; acc[2][3] += xv.z * wv.w;
        acc[3][0] += xv.w * wv.x; acc[3][1] += xv.w * wv.y; acc[3][2] += xv.w * wv.z; acc[3][3] += xv.w * wv.w;
    }

    float4 av = *(const float4*)(a_s + c0);
    float4 dv = *(const float4*)(a_d + c0);
    #pragma unroll
    for (int ri = 0; ri < 4; ++ri) {
        int grow = base + r0 + ri;
        float s1 = acc[ri][0] * av.x + acc[ri][1] * av.y + acc[ri][2] * av.z + acc[ri][3] * av.w;
        float s2 = acc[ri][0] * dv.x + acc[ri][1] * dv.y + acc[ri][2] * dv.z + acc[ri][3] * dv.w;
        #pragma unroll
        for (int d = 1; d <= 8; d <<= 1) { s1 += __shfl_xor(s1, d); s2 += __shfl_xor(s2, d); }
        if (grow < N) {
            uint2 o;
            o.x = bfpack(acc[ri][0], acc[ri][1]);
            o.y = bfpack(acc[ri][2], acc[ri][3]);
            *(uint2*)(hb + ((size_t)grow << 5) + (tx << 1)) = o;
            if (tx == 0) { as_[grow] = s1; ad_[grow] = s2; }
        }
    }
}

__global__ __launch_bounds__(256) void mm_tile_bf(const unsigned* __restrict__ in, const float* __restrict__ W,
                                                  const float* __restrict__ a_s, const float* __restrict__ a_d,
                                                  unsigned* __restrict__ hb, float* __restrict__ as_,
                                                  float* __restrict__ ad_, int N) {
    mm_tile_body<true>(blockIdx.x, in, W, a_s, a_d, hb, as_, ad_, N);
}

// layer-1 mm (f32 input) + atomic-free CSR scatter, role-split.
// R9: scatter now stores {src, dst} so the edge weight can be computed
// edge-parallel each layer (edge_w) instead of inside the per-node wave.
__global__ __launch_bounds__(256) void mm_fill(const float* __restrict__ in, const float* __restrict__ W,
                                               const float* __restrict__ a_s, const float* __restrict__ a_d,
                                               unsigned* __restrict__ hb, float* __restrict__ as_,
                                               float* __restrict__ ad_, int N, int nbt,
                                               const int* __restrict__ ei, const int* __restrict__ rank, int E,
                                               const int* __restrict__ offs, int2* __restrict__ csr_sd) {
    int bid = blockIdx.x;
    if (bid < nbt) {
        mm_tile_body<false>(bid, in, W, a_s, a_d, hb, as_, ad_, N);
    } else {
        int i = (bid - nbt) * 256 + threadIdx.x;
        int EP = E + N;
        if (i >= EP) return;
        int s, d;
        if (i < E) { s = ei[i]; d = ei[E + i]; } else { s = i - E; d = i - E; }
        csr_sd[offs[d] + rank[i]] = make_int2(s, d);
    }
}

// ---------------- edge-parallel weight precompute ----------------
// R9: w_e = exp(leaky(as_[src] + ad_[dst])) computed with full edge
// parallelism (coalesced int2 read, cached 4B gathers into 200KB as_/ad_,
// coalesced int2 write). Removes as_-gather + expf + shfl broadcasts from
// the node-wave critical path in gat_agg. ews = {src, bitcast(w)} in CSR
// order; 16-entry zero pad past EP keeps gat_agg's packet over-reads safe.
__global__ __launch_bounds__(256) void edge_w(const int2* __restrict__ csr_sd,
                                              const float* __restrict__ as_,
                                              const float* __restrict__ ad_,
                                              int2* __restrict__ ews, int EP) {
    int i = blockIdx.x * 256 + threadIdx.x;
    if (i < 16) ews[EP + i] = make_int2(0, 0);
    if (i >= EP) return;
    int2 sd = csr_sd[i];
    float e = as_[sd.x] + ad_[sd.y];
    e = (e > 0.f) ? e : 0.2f * e;
    float w = expf(e);
    ews[i] = make_int2(sd.x, __builtin_bit_cast(int, w));
}

// ---------------- per-node softmax-aggregate + bias + l2norm + relu ----------------
// R9 restructure: 2 nodes per wave (32 lanes each: 2 esub groups x 16 fg
// lanes), weights precomputed by edge_w. Per iteration each esub group loads
// 4 contiguous {src,w} pairs (8B broadcast loads, no shuffles) + 4 h-row
// gathers. Partial-packet masking via cndmask on w (over-read hits the next
// node's valid src with w forced 0, or the zero pad past EP). Per-wave chain:
// offs -> ews loads -> gathers -> FMA -> xor16 + fg-reduce; two independent
// node chains per wave double latency-hiding vs R8.
__global__ __launch_bounds__(256) void gat_agg(const unsigned* __restrict__ hb,
                                               const int2* __restrict__ ews,
                                               const int* __restrict__ offs,
                                               const float* __restrict__ bias,
                                               unsigned* __restrict__ outb, int N) {
    int tid = threadIdx.x, lane = tid & 63, wid = tid >> 6;
    int half = lane >> 5;
    int node = blockIdx.x * 8 + wid * 2 + half;
    int esub = (lane >> 4) & 1, fg = lane & 15;
    int start = 0, deg = 0;
    if (node < N) { start = offs[node]; deg = offs[node + 1] - start; }

    float a0 = 0.f, a1 = 0.f, a2 = 0.f, a3 = 0.f, sw = 0.f;
    for (int i0 = 0; i0 < deg; i0 += 8) {
        int eb = i0 + (esub << 2);
        int t = start + eb;
        int2 eA = ews[t];
        int2 eB = ews[t + 1];
        int2 eC = ews[t + 2];
        int2 eD = ews[t + 3];
        float wA = (eb + 0 < deg) ? __builtin_bit_cast(float, eA.y) : 0.f;
        float wB = (eb + 1 < deg) ? __builtin_bit_cast(float, eB.y) : 0.f;
        float wC = (eb + 2 < deg) ? __builtin_bit_cast(float, eC.y) : 0.f;
        float wD = (eb + 3 < deg) ? __builtin_bit_cast(float, eD.y) : 0.f;
        const uint2 hA = *(const uint2*)(hb + ((size_t)eA.x << 5) + (fg << 1));
        const uint2 hB = *(const uint2*)(hb + ((size_t)eB.x << 5) + (fg << 1));
        const uint2 hC = *(const uint2*)(hb + ((size_t)eC.x << 5) + (fg << 1));
        const uint2 hD = *(const uint2*)(hb + ((size_t)eD.x << 5) + (fg << 1));
        sw += wA + wB + wC + wD;
        a0 += wA * bflo(hA.x) + wB * bflo(hB.x) + wC * bflo(hC.x) + wD * bflo(hD.x);
        a1 += wA * bfhi(hA.x) + wB * bfhi(hB.x) + wC * bfhi(hC.x) + wD * bfhi(hD.x);
        a2 += wA * bflo(hA.y) + wB * bflo(hB.y) + wC * bflo(hC.y) + wD * bflo(hD.y);
        a3 += wA * bfhi(hA.y) + wB * bfhi(hB.y) + wC * bfhi(hC.y) + wD * bfhi(hD.y);
    }
    // combine the 2 esub groups (xor 16 stays inside each 32-lane half)
    a0 += __shfl_xor(a0, 16); a1 += __shfl_xor(a1, 16);
    a2 += __shfl_xor(a2, 16); a3 += __shfl_xor(a3, 16);
    sw += __shfl_xor(sw, 16);
    float inv = 1.f / (sw + 1e-16f);
    const float4 bv = *(const float4*)(bias + (fg << 2));
    float o0 = a0 * inv + bv.x, o1 = a1 * inv + bv.y, o2 = a2 * inv + bv.z, o3 = a3 * inv + bv.w;
    float n2 = o0 * o0 + o1 * o1 + o2 * o2 + o3 * o3;
    #pragma unroll
    for (int d = 1; d <= 8; d <<= 1) n2 += __shfl_xor(n2, d);   // across fg groups
    float innrm = 1.f / fmaxf(sqrtf(n2), 1e-12f);
    if (esub == 0 && node < N) {
        uint2 o;
        o.x = bfpack(fmaxf(o0 * innrm, 0.f), fmaxf(o1 * innrm, 0.f));
        o.y = bfpack(fmaxf(o2 * innrm, 0.f), fmaxf(o3 * innrm, 0.f));
        *(uint2*)(outb + ((size_t)node << 5) + (fg << 1)) = o;
    }
}

// ---------------- fused global_add_pool + MLP + log_softmax ----------------
// Block per graph: 4 waves stride the graph's node range (lane = feature,
// bf16 rows), LDS-reduce, wave 0 runs the 2-layer MLP + log_softmax.
__global__ __launch_bounds__(256) void pool_mlp(const unsigned short* __restrict__ hb, const int* __restrict__ gstart,
                                                const float* __restrict__ fc1w, const float* __restrict__ fc1b,
                                                const float* __restrict__ fc2w, const float* __restrict__ fc2b,
                                                float* __restrict__ out) {
    __shared__ float W1[DIM * DIM];
    __shared__ float red[4 * DIM];
    __shared__ float tbuf[DIM];
    __shared__ float obuf[CNUM];
    int tid = threadIdx.x, lane = tid & 63, wv = tid >> 6;
    int gid = blockIdx.x;

    const float4* W4 = (const float4*)fc1w;
    float4* W1s = (float4*)W1;
    #pragma unroll
    for (int i = 0; i < 4; ++i) W1s[tid + 256 * i] = W4[tid + 256 * i];

    int s = gstart[gid], e = gstart[gid + 1];
    float acc = 0.f;
    for (int i = s + wv; i < e; i += 4) acc += bfs(hb[((size_t)i << 6) + lane]);
    red[wv * DIM + lane] = acc;
    __syncthreads();

    if (wv == 0) {
        float g = red[lane] + red[DIM + lane] + red[2 * DIM + lane] + red[3 * DIM + lane];
        float t = fc1b[lane];
        #pragma unroll
        for (int k = 0; k < DIM; ++k) t += __shfl(g, k) * W1[k * DIM + lane];
        t = fmaxf(t, 0.f);
        tbuf[lane] = t;
        float o = 0.f;
        if (lane < CNUM) {
            o = fc2b[lane];
            #pragma unroll
            for (int k = 0; k < DIM; ++k) o += tbuf[k] * fc2w[k * CNUM + lane];
            obuf[lane] = o;
        }
        if (lane < CNUM) {
            float mx = obuf[0];
            #pragma unroll
            for (int k = 1; k < CNUM; ++k) mx = fmaxf(mx, obuf[k]);
            float ssum = 0.f;
            #pragma unroll
            for (int k = 0; k < CNUM; ++k) ssum += expf(obuf[k] - mx);
            out[gid * CNUM + lane] = o - mx - logf(ssum);
        }
    }
}

// ---------------- launch ----------------
static inline size_t align256(size_t x) { return (x + 255) & ~size_t(255); }

extern "C" void kernel_launch(void* const* d_in, const int* in_sizes, int n_in,
                              void* d_out, int out_size, void* d_ws, size_t ws_size,
                              hipStream_t stream) {
    const float* x     = (const float*)d_in[0];
    const int*   ei    = (const int*)d_in[1];
    const int*   batch = (const int*)d_in[2];
    const float* w1  = (const float*)d_in[3];
    const float* as1 = (const float*)d_in[4];
    const float* ad1 = (const float*)d_in[5];
    const float* b1  = (const float*)d_in[6];
    const float* w2  = (const float*)d_in[7];
    const float* as2 = (const float*)d_in[8];
    const float* ad2 = (const float*)d_in[9];
    const float* b2  = (const float*)d_in[10];
    const float* w3  = (const float*)d_in[11];
    const float* as3 = (const float*)d_in[12];
    const float* ad3 = (const float*)d_in[13];
    const float* b3  = (const float*)d_in[14];
    const float* fc1w = (const float*)d_in[15];
    const float* fc1b = (const float*)d_in[16];
    const float* fc2w = (const float*)d_in[17];
    const float* fc2b = (const float*)d_in[18];
    float* out = (float*)d_out;

    int N  = in_sizes[0] / DIM;
    int E  = in_sizes[1] / 2;
    int EP = E + N;
    int nb = (N + 255) / 256;   // scan blocks (<= 256 for N <= 65536)

    // workspace carve
    char* p = (char*)d_ws;
    unsigned* hbf = (unsigned*)p; p += align256(sizeof(unsigned) * (size_t)N * (DIM / 2));
    unsigned* oAb = (unsigned*)p; p += align256(sizeof(unsigned) * (size_t)N * (DIM / 2));
    unsigned* oBb = (unsigned*)p; p += align256(sizeof(unsigned) * (size_t)N * (DIM / 2));
    float* as_  = (float*)p; p += align256(sizeof(float) * (size_t)N);
    float* ad_  = (float*)p; p += align256(sizeof(float) * (size_t)N);
    int*   deg  = (int*)p;   p += align256(sizeof(int) * (size_t)N);
    int*   offs = (int*)p;   p += align256(sizeof(int) * (size_t)(N + 1));
    int*   rank = (int*)p;   p += align256(sizeof(int) * (size_t)EP);
    int2*  csr_sd = (int2*)p; p += align256(sizeof(int2) * (size_t)EP);
    int2*  ews  = (int2*)p;  p += align256(sizeof(int2) * (size_t)(EP + 16));
    int*   part = (int*)p;   p += align256(sizeof(int) * (size_t)nb);
    int*   gst  = (int*)p;   p += align256(sizeof(int) * (size_t)(GNUM + 1));

    int nblk = (N + 7) / 8;     // gat_agg: 8 nodes/block (2 per wave)
    int nbt = (N + 63) / 64;    // mm tiles
    int epBlocks = (EP + 255) / 256;

    // CSR build (dst-grouped; layer-invariant)
    hipMemsetAsync(deg, 0, sizeof(int) * (size_t)N, stream);
    deg_rank_kernel<<<epBlocks, 256, 0, stream>>>(ei, E, N, deg, rank);
    scan_misc<<<nb + 1, 256, 0, stream>>>(deg, part, N, nb, batch, N, gst);
    scan_down<<<nb, 256, 0, stream>>>(deg, part, offs, N);

    // layer 1 (mm + CSR scatter overlapped)
    mm_fill<<<nbt + epBlocks, 256, 0, stream>>>(x, w1, as1, ad1, hbf, as_, ad_, N, nbt,
                                                ei, rank, E, offs, csr_sd);
    edge_w<<<epBlocks, 256, 0, stream>>>(csr_sd, as_, ad_, ews, EP);
    gat_agg<<<nblk, 256, 0, stream>>>(hbf, ews, offs, b1, oAb, N);
    // layer 2
    mm_tile_bf<<<nbt, 256, 0, stream>>>(oAb, w2, as2, ad2, hbf, as_, ad_, N);
    edge_w<<<epBlocks, 256, 0, stream>>>(csr_sd, as_, ad_, ews, EP);
    gat_agg<<<nblk, 256, 0, stream>>>(hbf, ews, offs, b2, oBb, N);
    // layer 3
    mm_tile_bf<<<nbt, 256, 0, stream>>>(oBb, w3, as3, ad3, hbf, as_, ad_, N);
    edge_w<<<epBlocks, 256, 0, stream>>>(csr_sd, as_, ad_, ews, EP);
    gat_agg<<<nblk, 256, 0, stream>>>(hbf, ews, offs, b3, oAb, N);

    // fused pool + head (bf16 input)
    pool_mlp<<<GNUM, 256, 0, stream>>>((const unsigned short*)oAb, gst, fc1w, fc1b, fc2w, fc2b, out);
}

// Round 2
// 266.504 us; speedup vs baseline: 1.0900x; 1.0900x over previous
//
#include <hip/hip_runtime.h>
#include <hip/hip_bf16.h>
#include <math.h>

#define DIM 64
#define GNUM 256
#define CNUM 10

// bf16x2 pack/unpack (RNE). All intermediates (h, layer outputs) are bf16 for
// traffic; alpha/softmax math stays f32 (as_/ad_ from f32 accumulators).
__device__ __forceinline__ unsigned bfpack(float a, float b) {
    unsigned ua = __builtin_bit_cast(unsigned, a);
    unsigned ub = __builtin_bit_cast(unsigned, b);
    ua += 0x7fffu + ((ua >> 16) & 1u);
    ub += 0x7fffu + ((ub >> 16) & 1u);
    return (ua >> 16) | (ub & 0xffff0000u);
}
__device__ __forceinline__ float bflo(unsigned u) { return __builtin_bit_cast(float, u << 16); }
__device__ __forceinline__ float bfhi(unsigned u) { return __builtin_bit_cast(float, u & 0xffff0000u); }
__device__ __forceinline__ float bfs(unsigned short u) { return __builtin_bit_cast(float, (unsigned)u << 16); }

// ---------------- CSR build ----------------
__global__ void deg_rank_kernel(const int* __restrict__ ei, int E, int N,
                                int* __restrict__ deg, int* __restrict__ rank) {
    int i = blockIdx.x * blockDim.x + threadIdx.x;
    int EP = E + N;
    if (i >= EP) return;
    int d = (i < E) ? ei[E + i] : (i - E);   // row 1 of edge_index = dst; self loops appended
    rank[i] = atomicAdd(&deg[d], 1);
}

// scan_blocks + graph_bounds, role-split by blockIdx.
__global__ __launch_bounds__(256) void scan_misc(const int* __restrict__ deg, int* __restrict__ part, int n, int nb,
                                                 const int* __restrict__ batch, int N,
                                                 int* __restrict__ gstart) {
    int bid = blockIdx.x;
    if (bid < nb) {
        __shared__ int ws[4];
        int i = bid * 256 + threadIdx.x;
        int v = (i < n) ? deg[i] : 0;
        #pragma unroll
        for (int d = 32; d >= 1; d >>= 1) v += __shfl_xor(v, d);
        if ((threadIdx.x & 63) == 0) ws[threadIdx.x >> 6] = v;
        __syncthreads();
        if (threadIdx.x == 0) part[bid] = ws[0] + ws[1] + ws[2] + ws[3];
    } else {
        for (int g = threadIdx.x; g <= GNUM; g += 256) {
            int lo = 0, hi = N;
            while (lo < hi) { int mid = (lo + hi) >> 1; if (batch[mid] < g) lo = mid + 1; else hi = mid; }
            gstart[g] = lo;
        }
    }
}

// scan_down with the top-level scan fused (nb <= 256 for N <= 65536).
__global__ __launch_bounds__(256) void scan_down(const int* __restrict__ deg, const int* __restrict__ part,
                                                 int* __restrict__ offs, int n) {
    __shared__ int ws[4];
    __shared__ int base_s;
    int tid = threadIdx.x, lane = tid & 63, wid = tid >> 6;
    int pv = (tid < (int)blockIdx.x) ? part[tid] : 0;
    #pragma unroll
    for (int d = 32; d >= 1; d >>= 1) pv += __shfl_xor(pv, d);
    if (lane == 0) ws[wid] = pv;
    __syncthreads();
    if (tid == 0) base_s = ws[0] + ws[1] + ws[2] + ws[3];
    __syncthreads();
    int i = blockIdx.x * 256 + tid;
    int v = (i < n) ? deg[i] : 0;
    int x = v;
    #pragma unroll
    for (int d = 1; d < 64; d <<= 1) { int t = __shfl_up(x, d); if (lane >= d) x += t; }
    if (lane == 63) ws[wid] = x;
    __syncthreads();
    int add = base_s;
    for (int w = 0; w < wid; ++w) add += ws[w];
    if (i < n) offs[i] = add + x - v;
    if (i == n - 1) offs[n] = add + x;
}

// ---------------- tiled mm body ----------------
// 64x64 tile per block; x transposed into LDS (stride 68 floats). 4x4 register
// tile per thread. Input either f32 (layer 1) or packed bf16 (layers 2,3);
// h output always packed bf16 (R7: halves dominant gather traffic).
#define XSTR 68
template<bool BF16IN>
__device__ __forceinline__ void mm_tile_body(int bid,
                                             const void* __restrict__ in_, const float* __restrict__ W,
                                             const float* __restrict__ a_s, const float* __restrict__ a_d,
                                             unsigned* __restrict__ hb, float* __restrict__ as_,
                                             float* __restrict__ ad_, int N) {
    __shared__ float Ws[DIM * DIM];
    __shared__ float xT[XSTR * DIM];
    int tid = threadIdx.x;
    int base = bid * 64;

    const float4* W4 = (const float4*)W;
    float4* Ws4 = (float4*)Ws;
    #pragma unroll
    for (int i = 0; i < 4; ++i) Ws4[tid + 256 * i] = W4[tid + 256 * i];

    {
        int row = tid >> 2;
        int kb = (tid & 3) << 4;
        int grow = base + row;
        int crow = grow < N ? grow : N - 1;
        if (BF16IN) {
            const unsigned* xr = (const unsigned*)in_ + ((size_t)crow << 5) + (kb >> 1);
            uint4 u0 = *(const uint4*)xr;
            uint4 u1 = *(const uint4*)(xr + 4);
            xT[(kb + 0) * XSTR + row] = bflo(u0.x);  xT[(kb + 1) * XSTR + row] = bfhi(u0.x);
            xT[(kb + 2) * XSTR + row] = bflo(u0.y);  xT[(kb + 3) * XSTR + row] = bfhi(u0.y);
            xT[(kb + 4) * XSTR + row] = bflo(u0.z);  xT[(kb + 5) * XSTR + row] = bfhi(u0.z);
            xT[(kb + 6) * XSTR + row] = bflo(u0.w);  xT[(kb + 7) * XSTR + row] = bfhi(u0.w);
            xT[(kb + 8) * XSTR + row] = bflo(u1.x);  xT[(kb + 9) * XSTR + row] = bfhi(u1.x);
            xT[(kb + 10) * XSTR + row] = bflo(u1.y); xT[(kb + 11) * XSTR + row] = bfhi(u1.y);
            xT[(kb + 12) * XSTR + row] = bflo(u1.z); xT[(kb + 13) * XSTR + row] = bfhi(u1.z);
            xT[(kb + 14) * XSTR + row] = bflo(u1.w); xT[(kb + 15) * XSTR + row] = bfhi(u1.w);
        } else {
            const float4* xr = (const float4*)((const float*)in_ + ((size_t)crow << 6) + kb);
            float4 v0 = xr[0], v1 = xr[1], v2 = xr[2], v3 = xr[3];
            xT[(kb + 0) * XSTR + row] = v0.x;  xT[(kb + 1) * XSTR + row] = v0.y;
            xT[(kb + 2) * XSTR + row] = v0.z;  xT[(kb + 3) * XSTR + row] = v0.w;
            xT[(kb + 4) * XSTR + row] = v1.x;  xT[(kb + 5) * XSTR + row] = v1.y;
            xT[(kb + 6) * XSTR + row] = v1.z;  xT[(kb + 7) * XSTR + row] = v1.w;
            xT[(kb + 8) * XSTR + row] = v2.x;  xT[(kb + 9) * XSTR + row] = v2.y;
            xT[(kb + 10) * XSTR + row] = v2.z; xT[(kb + 11) * XSTR + row] = v2.w;
            xT[(kb + 12) * XSTR + row] = v3.x; xT[(kb + 13) * XSTR + row] = v3.y;
            xT[(kb + 14) * XSTR + row] = v3.z; xT[(kb + 15) * XSTR + row] = v3.w;
        }
    }
    __syncthreads();

    int tx = tid & 15, ty = tid >> 4;
    int c0 = tx << 2, r0 = ty << 2;
    float acc[4][4] = {{0.f}};
    #pragma unroll 8
    for (int k = 0; k < DIM; ++k) {
        float4 xv = *(const float4*)(xT + k * XSTR + r0);
        float4 wv = *(const float4*)(Ws + k * DIM + c0);
        acc[0][0] += xv.x * wv.x; acc[0][1] += xv.x * wv.y; acc[0][2] += xv.x * wv.z; acc[0][3] += xv.x * wv.w;
        acc[1][0] += xv.y * wv.x; acc[1][1] += xv.y * wv.y; acc[1][2] += xv.y * wv.z; acc[1][3] += xv.y * wv.w;
        acc[2][0] += xv.z * wv.x; acc[2][1] += xv.z * wv.y; acc[2][2] += xv.z * wv.z; acc[2][3] += xv.z * wv.w;
        acc[3][0] += xv.w * wv.x; acc[3][1] += xv.w * wv.y; acc[3][2] += xv.w * wv.z; acc[3][3] += xv.w * wv.w;
    }

    float4 av = *(const float4*)(a_s + c0);
    float4 dv = *(const float4*)(a_d + c0);
    #pragma unroll
    for (int ri = 0; ri < 4; ++ri) {
        int grow = base + r0 + ri;
        float s1 = acc[ri][0] * av.x + acc[ri][1] * av.y + acc[ri][2] * av.z + acc[ri][3] * av.w;
        float s2 = acc[ri][0] * dv.x + acc[ri][1] * dv.y + acc[ri][2] * dv.z + acc[ri][3] * dv.w;
        #pragma unroll
        for (int d = 1; d <= 8; d <<= 1) { s1 += __shfl_xor(s1, d); s2 += __shfl_xor(s2, d); }
        if (grow < N) {
            uint2 o;
            o.x = bfpack(acc[ri][0], acc[ri][1]);
            o.y = bfpack(acc[ri][2], acc[ri][3]);
            *(uint2*)(hb + ((size_t)grow << 5) + (tx << 1)) = o;
            if (tx == 0) { as_[grow] = s1; ad_[grow] = s2; }
        }
    }
}

__global__ __launch_bounds__(256) void mm_tile_bf(const unsigned* __restrict__ in, const float* __restrict__ W,
                                                  const float* __restrict__ a_s, const float* __restrict__ a_d,
                                                  unsigned* __restrict__ hb, float* __restrict__ as_,
                                                  float* __restrict__ ad_, int N) {
    mm_tile_body<true>(blockIdx.x, in, W, a_s, a_d, hb, as_, ad_, N);
}

// layer-1 mm (f32 input) + atomic-free CSR scatter, role-split.
// Scatter stores {src, dst} so gat_agg can compute edge weights block-locally.
__global__ __launch_bounds__(256) void mm_fill(const float* __restrict__ in, const float* __restrict__ W,
                                               const float* __restrict__ a_s, const float* __restrict__ a_d,
                                               unsigned* __restrict__ hb, float* __restrict__ as_,
                                               float* __restrict__ ad_, int N, int nbt,
                                               const int* __restrict__ ei, const int* __restrict__ rank, int E,
                                               const int* __restrict__ offs, int2* __restrict__ csr_sd) {
    int bid = blockIdx.x;
    if (bid < nbt) {
        mm_tile_body<false>(bid, in, W, a_s, a_d, hb, as_, ad_, N);
    } else {
        int i = (bid - nbt) * 256 + threadIdx.x;
        int EP = E + N;
        if (i >= EP) return;
        int s, d;
        if (i < E) { s = ei[i]; d = ei[E + i]; } else { s = i - E; d = i - E; }
        csr_sd[offs[d] + rank[i]] = make_int2(s, d);
    }
}

// ---------------- per-node softmax-aggregate + bias + l2norm + relu ----------------
// R10: block owns 32 consecutive nodes = one contiguous CSR slice. Phase 1
// (block-parallel): compute {src, w=exp(leaky(as_[s]+ad_[d]))} for the slice
// into LDS (ad_ of the block's 32 dst nodes preloaded; coalesced csr_sd read).
// Phase 2: 8 lanes per node (fg = feature quad of 8 bf16 = uint4 gather),
// 4 edges/packet from LDS broadcast. No ews global round-trip, no edge_w
// kernels, sw complete per-lane (no reduction), 8 independent chains/wave.
// Fallback path (global csr_sd + inline w, clamped) for blocks whose edge
// count exceeds the LDS cache (impossible for this input: mean 544, cap 2048).
#define AGG_NPB 32
#define AGG_CAP 2048
__global__ __launch_bounds__(256) void gat_agg(const unsigned* __restrict__ hb,
                                               const int2* __restrict__ csr_sd,
                                               const float* __restrict__ as_,
                                               const float* __restrict__ ad_,
                                               const int* __restrict__ offs,
                                               const float* __restrict__ bias,
                                               unsigned* __restrict__ outb, int N) {
    __shared__ int soffs[AGG_NPB + 1];
    __shared__ float adl[AGG_NPB];
    __shared__ int2 lsw[AGG_CAP + 4];
    int tid = threadIdx.x;
    int base = blockIdx.x * AGG_NPB;
    if (tid <= AGG_NPB) {
        int n = base + tid;
        soffs[tid] = offs[n < N ? n : N];
    }
    if (tid < AGG_NPB) {
        int n = base + tid;
        adl[tid] = (n < N) ? ad_[n] : 0.f;
    }
    __syncthreads();
    int estart = soffs[0];
    int nE = soffs[AGG_NPB] - estart;
    bool inLds = (nE <= AGG_CAP);
    if (inLds) {
        for (int i = tid; i < nE; i += 256) {
            int2 sd = csr_sd[estart + i];
            float e = as_[sd.x] + adl[sd.y - base];
            e = (e > 0.f) ? e : 0.2f * e;
            lsw[i] = make_int2(sd.x, __builtin_bit_cast(int, expf(e)));
        }
        if (tid < 4) lsw[nE + tid] = make_int2(0, 0);
    }
    __syncthreads();

    int lane = tid & 63, wid = tid >> 6;
    int sub = lane >> 3, fg = lane & 7;          // 8 node-groups/wave, 8 lanes each
    int li = (wid << 3) + sub;                   // local node 0..31
    int node = base + li;
    int ls = soffs[li] - estart;
    int deg = soffs[li + 1] - soffs[li];

    float a0 = 0.f, a1 = 0.f, a2 = 0.f, a3 = 0.f;
    float a4 = 0.f, a5 = 0.f, a6 = 0.f, a7 = 0.f, sw = 0.f;
    if (inLds) {
        for (int eb = 0; eb < deg; eb += 4) {
            int t = ls + eb;
            int2 eA = lsw[t], eB = lsw[t + 1], eC = lsw[t + 2], eD = lsw[t + 3];
            float wA = __builtin_bit_cast(float, eA.y);
            float wB = (eb + 1 < deg) ? __builtin_bit_cast(float, eB.y) : 0.f;
            float wC = (eb + 2 < deg) ? __builtin_bit_cast(float, eC.y) : 0.f;
            float wD = (eb + 3 < deg) ? __builtin_bit_cast(float, eD.y) : 0.f;
            const uint4 hA = *(const uint4*)(hb + ((size_t)eA.x << 5) + (fg << 2));
            const uint4 hB = *(const uint4*)(hb + ((size_t)eB.x << 5) + (fg << 2));
            const uint4 hC = *(const uint4*)(hb + ((size_t)eC.x << 5) + (fg << 2));
            const uint4 hD = *(const uint4*)(hb + ((size_t)eD.x << 5) + (fg << 2));
            sw += wA + wB + wC + wD;
            a0 += wA * bflo(hA.x) + wB * bflo(hB.x) + wC * bflo(hC.x) + wD * bflo(hD.x);
            a1 += wA * bfhi(hA.x) + wB * bfhi(hB.x) + wC * bfhi(hC.x) + wD * bfhi(hD.x);
            a2 += wA * bflo(hA.y) + wB * bflo(hB.y) + wC * bflo(hC.y) + wD * bflo(hD.y);
            a3 += wA * bfhi(hA.y) + wB * bfhi(hB.y) + wC * bfhi(hC.y) + wD * bfhi(hD.y);
            a4 += wA * bflo(hA.z) + wB * bflo(hB.z) + wC * bflo(hC.z) + wD * bflo(hD.z);
            a5 += wA * bfhi(hA.z) + wB * bfhi(hB.z) + wC * bfhi(hC.z) + wD * bfhi(hD.z);
            a6 += wA * bflo(hA.w) + wB * bflo(hB.w) + wC * bflo(hC.w) + wD * bflo(hD.w);
            a7 += wA * bfhi(hA.w) + wB * bfhi(hB.w) + wC * bfhi(hC.w) + wD * bfhi(hD.w);
        }
    } else {
        // cold fallback: same math from global, fully clamped/masked
        float adi = (node < N) ? ad_[node] : 0.f;
        for (int eb = 0; eb < deg; eb += 4) {
            int t = estart + ls + eb;
            float wv[4]; int sv[4];
            #pragma unroll
            for (int k = 0; k < 4; ++k) {
                int tt = t + k;
                int2 sd = (eb + k < deg) ? csr_sd[tt] : make_int2(0, 0);
                int s = sd.x; s = s < 0 ? 0 : (s >= N ? N - 1 : s);
                float e = as_[s] + adi;
                e = (e > 0.f) ? e : 0.2f * e;
                wv[k] = (eb + k < deg) ? expf(e) : 0.f;
                sv[k] = s;
            }
            #pragma unroll
            for (int k = 0; k < 4; ++k) {
                const uint4 hv = *(const uint4*)(hb + ((size_t)sv[k] << 5) + (fg << 2));
                sw += wv[k];
                a0 += wv[k] * bflo(hv.x); a1 += wv[k] * bfhi(hv.x);
                a2 += wv[k] * bflo(hv.y); a3 += wv[k] * bfhi(hv.y);
                a4 += wv[k] * bflo(hv.z); a5 += wv[k] * bfhi(hv.z);
                a6 += wv[k] * bflo(hv.w); a7 += wv[k] * bfhi(hv.w);
            }
        }
    }

    float inv = 1.f / (sw + 1e-16f);
    const float4 b0 = *(const float4*)(bias + (fg << 3));
    const float4 b1 = *(const float4*)(bias + (fg << 3) + 4);
    float o0 = a0 * inv + b0.x, o1 = a1 * inv + b0.y, o2 = a2 * inv + b0.z, o3 = a3 * inv + b0.w;
    float o4 = a4 * inv + b1.x, o5 = a5 * inv + b1.y, o6 = a6 * inv + b1.z, o7 = a7 * inv + b1.w;
    float n2 = o0 * o0 + o1 * o1 + o2 * o2 + o3 * o3 + o4 * o4 + o5 * o5 + o6 * o6 + o7 * o7;
    #pragma unroll
    for (int d = 1; d <= 4; d <<= 1) n2 += __shfl_xor(n2, d);   // across the 8 fg lanes
    float innrm = 1.f / fmaxf(sqrtf(n2), 1e-12f);
    if (node < N) {
        uint4 o;
        o.x = bfpack(fmaxf(o0 * innrm, 0.f), fmaxf(o1 * innrm, 0.f));
        o.y = bfpack(fmaxf(o2 * innrm, 0.f), fmaxf(o3 * innrm, 0.f));
        o.z = bfpack(fmaxf(o4 * innrm, 0.f), fmaxf(o5 * innrm, 0.f));
        o.w = bfpack(fmaxf(o6 * innrm, 0.f), fmaxf(o7 * innrm, 0.f));
        *(uint4*)(outb + ((size_t)node << 5) + (fg << 2)) = o;
    }
}

// ---------------- fused global_add_pool + MLP + log_softmax ----------------
// Block per graph: 4 waves stride the graph's node range (lane = feature,
// bf16 rows), LDS-reduce, wave 0 runs the 2-layer MLP + log_softmax.
__global__ __launch_bounds__(256) void pool_mlp(const unsigned short* __restrict__ hb, const int* __restrict__ gstart,
                                                const float* __restrict__ fc1w, const float* __restrict__ fc1b,
                                                const float* __restrict__ fc2w, const float* __restrict__ fc2b,
                                                float* __restrict__ out) {
    __shared__ float W1[DIM * DIM];
    __shared__ float red[4 * DIM];
    __shared__ float tbuf[DIM];
    __shared__ float obuf[CNUM];
    int tid = threadIdx.x, lane = tid & 63, wv = tid >> 6;
    int gid = blockIdx.x;

    const float4* W4 = (const float4*)fc1w;
    float4* W1s = (float4*)W1;
    #pragma unroll
    for (int i = 0; i < 4; ++i) W1s[tid + 256 * i] = W4[tid + 256 * i];

    int s = gstart[gid], e = gstart[gid + 1];
    float acc = 0.f;
    for (int i = s + wv; i < e; i += 4) acc += bfs(hb[((size_t)i << 6) + lane]);
    red[wv * DIM + lane] = acc;
    __syncthreads();

    if (wv == 0) {
        float g = red[lane] + red[DIM + lane] + red[2 * DIM + lane] + red[3 * DIM + lane];
        float t = fc1b[lane];
        #pragma unroll
        for (int k = 0; k < DIM; ++k) t += __shfl(g, k) * W1[k * DIM + lane];
        t = fmaxf(t, 0.f);
        tbuf[lane] = t;
        float o = 0.f;
        if (lane < CNUM) {
            o = fc2b[lane];
            #pragma unroll
            for (int k = 0; k < DIM; ++k) o += tbuf[k] * fc2w[k * CNUM + lane];
            obuf[lane] = o;
        }
        if (lane < CNUM) {
            float mx = obuf[0];
            #pragma unroll
            for (int k = 1; k < CNUM; ++k) mx = fmaxf(mx, obuf[k]);
            float ssum = 0.f;
            #pragma unroll
            for (int k = 0; k < CNUM; ++k) ssum += expf(obuf[k] - mx);
            out[gid * CNUM + lane] = o - mx - logf(ssum);
        }
    }
}

// ---------------- launch ----------------
static inline size_t align256(size_t x) { return (x + 255) & ~size_t(255); }

extern "C" void kernel_launch(void* const* d_in, const int* in_sizes, int n_in,
                              void* d_out, int out_size, void* d_ws, size_t ws_size,
                              hipStream_t stream) {
    const float* x     = (const float*)d_in[0];
    const int*   ei    = (const int*)d_in[1];
    const int*   batch = (const int*)d_in[2];
    const float* w1  = (const float*)d_in[3];
    const float* as1 = (const float*)d_in[4];
    const float* ad1 = (const float*)d_in[5];
    const float* b1  = (const float*)d_in[6];
    const float* w2  = (const float*)d_in[7];
    const float* as2 = (const float*)d_in[8];
    const float* ad2 = (const float*)d_in[9];
    const float* b2  = (const float*)d_in[10];
    const float* w3  = (const float*)d_in[11];
    const float* as3 = (const float*)d_in[12];
    const float* ad3 = (const float*)d_in[13];
    const float* b3  = (const float*)d_in[14];
    const float* fc1w = (const float*)d_in[15];
    const float* fc1b = (const float*)d_in[16];
    const float* fc2w = (const float*)d_in[17];
    const float* fc2b = (const float*)d_in[18];
    float* out = (float*)d_out;

    int N  = in_sizes[0] / DIM;
    int E  = in_sizes[1] / 2;
    int EP = E + N;
    int nb = (N + 255) / 256;   // scan blocks (<= 256 for N <= 65536)

    // workspace carve
    char* p = (char*)d_ws;
    unsigned* hbf = (unsigned*)p; p += align256(sizeof(unsigned) * (size_t)N * (DIM / 2));
    unsigned* oAb = (unsigned*)p; p += align256(sizeof(unsigned) * (size_t)N * (DIM / 2));
    unsigned* oBb = (unsigned*)p; p += align256(sizeof(unsigned) * (size_t)N * (DIM / 2));
    float* as_  = (float*)p; p += align256(sizeof(float) * (size_t)N);
    float* ad_  = (float*)p; p += align256(sizeof(float) * (size_t)N);
    int*   deg  = (int*)p;   p += align256(sizeof(int) * (size_t)N);
    int*   offs = (int*)p;   p += align256(sizeof(int) * (size_t)(N + 1));
    int*   rank = (int*)p;   p += align256(sizeof(int) * (size_t)EP);
    int2*  csr_sd = (int2*)p; p += align256(sizeof(int2) * (size_t)EP);
    int*   part = (int*)p;   p += align256(sizeof(int) * (size_t)nb);
    int*   gst  = (int*)p;   p += align256(sizeof(int) * (size_t)(GNUM + 1));

    int nblk = (N + AGG_NPB - 1) / AGG_NPB;   // gat_agg: 32 nodes/block
    int nbt = (N + 63) / 64;                  // mm tiles
    int epBlocks = (EP + 255) / 256;

    // CSR build (dst-grouped; layer-invariant)
    hipMemsetAsync(deg, 0, sizeof(int) * (size_t)N, stream);
    deg_rank_kernel<<<epBlocks, 256, 0, stream>>>(ei, E, N, deg, rank);
    scan_misc<<<nb + 1, 256, 0, stream>>>(deg, part, N, nb, batch, N, gst);
    scan_down<<<nb, 256, 0, stream>>>(deg, part, offs, N);

    // layer 1 (mm + CSR scatter overlapped)
    mm_fill<<<nbt + epBlocks, 256, 0, stream>>>(x, w1, as1, ad1, hbf, as_, ad_, N, nbt,
                                                ei, rank, E, offs, csr_sd);
    gat_agg<<<nblk, 256, 0, stream>>>(hbf, csr_sd, as_, ad_, offs, b1, oAb, N);
    // layer 2
    mm_tile_bf<<<nbt, 256, 0, stream>>>(oAb, w2, as2, ad2, hbf, as_, ad_, N);
    gat_agg<<<nblk, 256, 0, stream>>>(hbf, csr_sd, as_, ad_, offs, b2, oBb, N);
    // layer 3
    mm_tile_bf<<<nbt, 256, 0, stream>>>(oBb, w3, as3, ad3, hbf, as_, ad_, N);
    gat_agg<<<nblk, 256, 0, stream>>>(hbf, csr_sd, as_, ad_, offs, b3, oAb, N);

    // fused pool + head (bf16 input)
    pool_mlp<<<GNUM, 256, 0, stream>>>((const unsigned short*)oAb, gst, fc1w, fc1b, fc2w, fc2b, out);
}

// Round 3
// 250.492 us; speedup vs baseline: 1.1596x; 1.0639x over previous
//
#include <hip/hip_runtime.h>
#include <hip/hip_bf16.h>
#include <math.h>

#define DIM 64
#define GNUM 256
#define CNUM 10

// bf16x2 pack/unpack (RNE). h intermediates are bf16 for gather traffic;
// alpha/softmax math stays f32.
__device__ __forceinline__ unsigned bfpack(float a, float b) {
    unsigned ua = __builtin_bit_cast(unsigned, a);
    unsigned ub = __builtin_bit_cast(unsigned, b);
    ua += 0x7fffu + ((ua >> 16) & 1u);
    ub += 0x7fffu + ((ub >> 16) & 1u);
    return (ua >> 16) | (ub & 0xffff0000u);
}
__device__ __forceinline__ float bflo(unsigned u) { return __builtin_bit_cast(float, u << 16); }
__device__ __forceinline__ float bfhi(unsigned u) { return __builtin_bit_cast(float, u & 0xffff0000u); }
__device__ __forceinline__ float bfs(unsigned short u) { return __builtin_bit_cast(float, (unsigned)u << 16); }

// ---------------- CSR build ----------------
__global__ void deg_rank_kernel(const int* __restrict__ ei, int E, int N,
                                int* __restrict__ deg, int* __restrict__ rank) {
    int i = blockIdx.x * blockDim.x + threadIdx.x;
    int EP = E + N;
    if (i >= EP) return;
    int d = (i < E) ? ei[E + i] : (i - E);   // row 1 of edge_index = dst; self loops appended
    rank[i] = atomicAdd(&deg[d], 1);
}

// scan_blocks + graph_bounds, role-split by blockIdx.
__global__ __launch_bounds__(256) void scan_misc(const int* __restrict__ deg, int* __restrict__ part, int n, int nb,
                                                 const int* __restrict__ batch, int N,
                                                 int* __restrict__ gstart) {
    int bid = blockIdx.x;
    if (bid < nb) {
        __shared__ int ws[4];
        int i = bid * 256 + threadIdx.x;
        int v = (i < n) ? deg[i] : 0;
        #pragma unroll
        for (int d = 32; d >= 1; d >>= 1) v += __shfl_xor(v, d);
        if ((threadIdx.x & 63) == 0) ws[threadIdx.x >> 6] = v;
        __syncthreads();
        if (threadIdx.x == 0) part[bid] = ws[0] + ws[1] + ws[2] + ws[3];
    } else {
        for (int g = threadIdx.x; g <= GNUM; g += 256) {
            int lo = 0, hi = N;
            while (lo < hi) { int mid = (lo + hi) >> 1; if (batch[mid] < g) lo = mid + 1; else hi = mid; }
            gstart[g] = lo;
        }
    }
}

// scan_down with the top-level scan fused (nb <= 256 for N <= 65536).
__global__ __launch_bounds__(256) void scan_down(const int* __restrict__ deg, const int* __restrict__ part,
                                                 int* __restrict__ offs, int n) {
    __shared__ int ws[4];
    __shared__ int base_s;
    int tid = threadIdx.x, lane = tid & 63, wid = tid >> 6;
    int pv = (tid < (int)blockIdx.x) ? part[tid] : 0;
    #pragma unroll
    for (int d = 32; d >= 1; d >>= 1) pv += __shfl_xor(pv, d);
    if (lane == 0) ws[wid] = pv;
    __syncthreads();
    if (tid == 0) base_s = ws[0] + ws[1] + ws[2] + ws[3];
    __syncthreads();
    int i = blockIdx.x * 256 + tid;
    int v = (i < n) ? deg[i] : 0;
    int x = v;
    #pragma unroll
    for (int d = 1; d < 64; d <<= 1) { int t = __shfl_up(x, d); if (lane >= d) x += t; }
    if (lane == 63) ws[wid] = x;
    __syncthreads();
    int add = base_s;
    for (int w = 0; w < wid; ++w) add += ws[w];
    if (i < n) offs[i] = add + x - v;
    if (i == n - 1) offs[n] = add + x;
}

// ---------------- tiled mm body (layer 1, f32 input) ----------------
#define XSTR 68
__device__ __forceinline__ void mm_tile_body_f32(int bid,
                                                 const float* __restrict__ in_, const float* __restrict__ W,
                                                 const float* __restrict__ a_s, const float* __restrict__ a_d,
                                                 unsigned* __restrict__ hb, float* __restrict__ as_,
                                                 float* __restrict__ ad_, int N) {
    __shared__ float Ws[DIM * DIM];
    __shared__ float xT[XSTR * DIM];
    int tid = threadIdx.x;
    int base = bid * 64;

    const float4* W4 = (const float4*)W;
    float4* Ws4 = (float4*)Ws;
    #pragma unroll
    for (int i = 0; i < 4; ++i) Ws4[tid + 256 * i] = W4[tid + 256 * i];

    {
        int row = tid >> 2;
        int kb = (tid & 3) << 4;
        int grow = base + row;
        int crow = grow < N ? grow : N - 1;
        const float4* xr = (const float4*)(in_ + ((size_t)crow << 6) + kb);
        float4 v0 = xr[0], v1 = xr[1], v2 = xr[2], v3 = xr[3];
        xT[(kb + 0) * XSTR + row] = v0.x;  xT[(kb + 1) * XSTR + row] = v0.y;
        xT[(kb + 2) * XSTR + row] = v0.z;  xT[(kb + 3) * XSTR + row] = v0.w;
        xT[(kb + 4) * XSTR + row] = v1.x;  xT[(kb + 5) * XSTR + row] = v1.y;
        xT[(kb + 6) * XSTR + row] = v1.z;  xT[(kb + 7) * XSTR + row] = v1.w;
        xT[(kb + 8) * XSTR + row] = v2.x;  xT[(kb + 9) * XSTR + row] = v2.y;
        xT[(kb + 10) * XSTR + row] = v2.z; xT[(kb + 11) * XSTR + row] = v2.w;
        xT[(kb + 12) * XSTR + row] = v3.x; xT[(kb + 13) * XSTR + row] = v3.y;
        xT[(kb + 14) * XSTR + row] = v3.z; xT[(kb + 15) * XSTR + row] = v3.w;
    }
    __syncthreads();

    int tx = tid & 15, ty = tid >> 4;
    int c0 = tx << 2, r0 = ty << 2;
    float acc[4][4] = {{0.f}};
    #pragma unroll 8
    for (int k = 0; k < DIM; ++k) {
        float4 xv = *(const float4*)(xT + k * XSTR + r0);
        float4 wv = *(const float4*)(Ws + k * DIM + c0);
        acc[0][0] += xv.x * wv.x; acc[0][1] += xv.x * wv.y; acc[0][2] += xv.x * wv.z; acc[0][3] += xv.x * wv.w;
        acc[1][0] += xv.y * wv.x; acc[1][1] += xv.y * wv.y; acc[1][2] += xv.y * wv.z; acc[1][3] += xv.y * wv.w;
        acc[2][0] += xv.z * wv.x; acc[2][1] += xv.z * wv.y; acc[2][2] += xv.z * wv.z; acc[2][3] += xv.z * wv.w;
        acc[3][0] += xv.w * wv.x; acc[3][1] += xv.w * wv.y; acc[3][2] += xv.w * wv.z; acc[3][3] += xv.w * wv.w;
    }

    float4 av = *(const float4*)(a_s + c0);
    float4 dv = *(const float4*)(a_d + c0);
    #pragma unroll
    for (int ri = 0; ri < 4; ++ri) {
        int grow = base + r0 + ri;
        float s1 = acc[ri][0] * av.x + acc[ri][1] * av.y + acc[ri][2] * av.z + acc[ri][3] * av.w;
        float s2 = acc[ri][0] * dv.x + acc[ri][1] * dv.y + acc[ri][2] * dv.z + acc[ri][3] * dv.w;
        #pragma unroll
        for (int d = 1; d <= 8; d <<= 1) { s1 += __shfl_xor(s1, d); s2 += __shfl_xor(s2, d); }
        if (grow < N) {
            uint2 o;
            o.x = bfpack(acc[ri][0], acc[ri][1]);
            o.y = bfpack(acc[ri][2], acc[ri][3]);
            *(uint2*)(hb + ((size_t)grow << 5) + (tx << 1)) = o;
            if (tx == 0) { as_[grow] = s1; ad_[grow] = s2; }
        }
    }
}

// layer-1 mm (f32 input) + atomic-free CSR scatter, role-split.
__global__ __launch_bounds__(256) void mm_fill(const float* __restrict__ in, const float* __restrict__ W,
                                               const float* __restrict__ a_s, const float* __restrict__ a_d,
                                               unsigned* __restrict__ hb, float* __restrict__ as_,
                                               float* __restrict__ ad_, int N, int nbt,
                                               const int* __restrict__ ei, const int* __restrict__ rank, int E,
                                               const int* __restrict__ offs, int2* __restrict__ csr_sd) {
    int bid = blockIdx.x;
    if (bid < nbt) {
        mm_tile_body_f32(bid, in, W, a_s, a_d, hb, as_, ad_, N);
    } else {
        int i = (bid - nbt) * 256 + threadIdx.x;
        int EP = E + N;
        if (i >= EP) return;
        int s, d;
        if (i < E) { s = ei[i]; d = ei[E + i]; } else { s = i - E; d = i - E; }
        csr_sd[offs[d] + rank[i]] = make_int2(s, d);
    }
}

// ---------------- fused agg(layer k) + mm(layer k+1) ----------------
// R11: block owns 64 consecutive nodes = one contiguous CSR slice.
// Phase 1: edge weights {src, w} into LDS (block-parallel, coalesced).
// Phase 2: 8 lanes/node, 2 passes of 32 nodes; aggregate + bias + l2norm +
// relu; write results DIRECTLY into the mm's transposed xT LDS tile (no
// global round-trip of the layer output).
// Phase 3: load W into the edge-cache LDS region (union; agg done), run the
// 64x64 mm, emit next layer's hb (bf16) + as_/ad_.
// Ping-pong buffers outside: reads layer-k hb/as/ad, writes layer-k+1 set.
#define FUS_NPB 64
#define FUS_CAP 2560
__global__ __launch_bounds__(256) void agg_mm(const unsigned* __restrict__ hbp,
                                              const int2* __restrict__ csr_sd,
                                              const float* __restrict__ asp,
                                              const float* __restrict__ adp,
                                              const int* __restrict__ offs,
                                              const float* __restrict__ bias,
                                              const float* __restrict__ W,
                                              const float* __restrict__ a_s,
                                              const float* __restrict__ a_d,
                                              unsigned* __restrict__ hbn,
                                              float* __restrict__ asn,
                                              float* __restrict__ adn, int N) {
    __shared__ int soffs[FUS_NPB + 1];
    __shared__ float adl[FUS_NPB];
    __shared__ int2 lsw[FUS_CAP + 4];          // 20 KB; reused as Ws (16 KB) in phase 3
    __shared__ float xT[XSTR * DIM];           // 17.4 KB
    float* Ws = (float*)lsw;

    int tid = threadIdx.x;
    int base = blockIdx.x * FUS_NPB;
    if (tid <= FUS_NPB) {
        int n = base + tid;
        soffs[tid] = offs[n < N ? n : N];
    }
    if (tid < FUS_NPB) {
        int n = base + tid;
        adl[tid] = (n < N) ? adp[n] : 0.f;
    }
    __syncthreads();
    int estart = soffs[0];
    int nE = soffs[FUS_NPB] - estart;
    bool inLds = (nE <= FUS_CAP);
    if (inLds) {
        for (int i = tid; i < nE; i += 256) {
            int2 sd = csr_sd[estart + i];
            float e = asp[sd.x] + adl[sd.y - base];
            e = (e > 0.f) ? e : 0.2f * e;
            lsw[i] = make_int2(sd.x, __builtin_bit_cast(int, expf(e)));
        }
        if (tid < 4) lsw[nE + tid] = make_int2(0, 0);
    }
    __syncthreads();

    int lane = tid & 63, wid = tid >> 6;
    int sub = lane >> 3, fg = lane & 7;        // 8 node-groups/wave, 8 lanes each

    #pragma unroll
    for (int p = 0; p < 2; ++p) {
        int li = p * 32 + (wid << 3) + sub;    // local node 0..63
        int node = base + li;
        int ls = soffs[li] - estart;
        int deg = soffs[li + 1] - soffs[li];

        float a0 = 0.f, a1 = 0.f, a2 = 0.f, a3 = 0.f;
        float a4 = 0.f, a5 = 0.f, a6 = 0.f, a7 = 0.f, sw = 0.f;
        if (inLds) {
            for (int eb = 0; eb < deg; eb += 4) {
                int t = ls + eb;
                int2 eA = lsw[t], eB = lsw[t + 1], eC = lsw[t + 2], eD = lsw[t + 3];
                float wA = __builtin_bit_cast(float, eA.y);
                float wB = (eb + 1 < deg) ? __builtin_bit_cast(float, eB.y) : 0.f;
                float wC = (eb + 2 < deg) ? __builtin_bit_cast(float, eC.y) : 0.f;
                float wD = (eb + 3 < deg) ? __builtin_bit_cast(float, eD.y) : 0.f;
                const uint4 hA = *(const uint4*)(hbp + ((size_t)eA.x << 5) + (fg << 2));
                const uint4 hB = *(const uint4*)(hbp + ((size_t)eB.x << 5) + (fg << 2));
                const uint4 hC = *(const uint4*)(hbp + ((size_t)eC.x << 5) + (fg << 2));
                const uint4 hD = *(const uint4*)(hbp + ((size_t)eD.x << 5) + (fg << 2));
                sw += wA + wB + wC + wD;
                a0 += wA * bflo(hA.x) + wB * bflo(hB.x) + wC * bflo(hC.x) + wD * bflo(hD.x);
                a1 += wA * bfhi(hA.x) + wB * bfhi(hB.x) + wC * bfhi(hC.x) + wD * bfhi(hD.x);
                a2 += wA * bflo(hA.y) + wB * bflo(hB.y) + wC * bflo(hC.y) + wD * bflo(hD.y);
                a3 += wA * bfhi(hA.y) + wB * bfhi(hB.y) + wC * bfhi(hC.y) + wD * bfhi(hD.y);
                a4 += wA * bflo(hA.z) + wB * bflo(hB.z) + wC * bflo(hC.z) + wD * bflo(hD.z);
                a5 += wA * bfhi(hA.z) + wB * bfhi(hB.z) + wC * bfhi(hC.z) + wD * bfhi(hD.z);
                a6 += wA * bflo(hA.w) + wB * bflo(hB.w) + wC * bflo(hC.w) + wD * bflo(hD.w);
                a7 += wA * bfhi(hA.w) + wB * bfhi(hB.w) + wC * bfhi(hC.w) + wD * bfhi(hD.w);
            }
        } else {
            // cold fallback: same math from global, fully clamped/masked
            float adi = adl[li];
            for (int eb = 0; eb < deg; eb += 4) {
                int t = estart + ls + eb;
                float wv[4]; int sv[4];
                #pragma unroll
                for (int k = 0; k < 4; ++k) {
                    int2 sd = (eb + k < deg) ? csr_sd[t + k] : make_int2(0, 0);
                    int s = sd.x; s = s < 0 ? 0 : (s >= N ? N - 1 : s);
                    float e = asp[s] + adi;
                    e = (e > 0.f) ? e : 0.2f * e;
                    wv[k] = (eb + k < deg) ? expf(e) : 0.f;
                    sv[k] = s;
                }
                #pragma unroll
                for (int k = 0; k < 4; ++k) {
                    const uint4 hv = *(const uint4*)(hbp + ((size_t)sv[k] << 5) + (fg << 2));
                    sw += wv[k];
                    a0 += wv[k] * bflo(hv.x); a1 += wv[k] * bfhi(hv.x);
                    a2 += wv[k] * bflo(hv.y); a3 += wv[k] * bfhi(hv.y);
                    a4 += wv[k] * bflo(hv.z); a5 += wv[k] * bfhi(hv.z);
                    a6 += wv[k] * bflo(hv.w); a7 += wv[k] * bfhi(hv.w);
                }
            }
        }

        float inv = 1.f / (sw + 1e-16f);
        const float4 b0 = *(const float4*)(bias + (fg << 3));
        const float4 b1 = *(const float4*)(bias + (fg << 3) + 4);
        float o0 = a0 * inv + b0.x, o1 = a1 * inv + b0.y, o2 = a2 * inv + b0.z, o3 = a3 * inv + b0.w;
        float o4 = a4 * inv + b1.x, o5 = a5 * inv + b1.y, o6 = a6 * inv + b1.z, o7 = a7 * inv + b1.w;
        float n2 = o0 * o0 + o1 * o1 + o2 * o2 + o3 * o3 + o4 * o4 + o5 * o5 + o6 * o6 + o7 * o7;
        #pragma unroll
        for (int d = 1; d <= 4; d <<= 1) n2 += __shfl_xor(n2, d);   // across the 8 fg lanes
        float innrm = 1.f / fmaxf(sqrtf(n2), 1e-12f);
        if (node >= N) innrm = 0.f;            // keep xT clean for pad rows
        int kb = fg << 3;
        xT[(kb + 0) * XSTR + li] = fmaxf(o0 * innrm, 0.f);
        xT[(kb + 1) * XSTR + li] = fmaxf(o1 * innrm, 0.f);
        xT[(kb + 2) * XSTR + li] = fmaxf(o2 * innrm, 0.f);
        xT[(kb + 3) * XSTR + li] = fmaxf(o3 * innrm, 0.f);
        xT[(kb + 4) * XSTR + li] = fmaxf(o4 * innrm, 0.f);
        xT[(kb + 5) * XSTR + li] = fmaxf(o5 * innrm, 0.f);
        xT[(kb + 6) * XSTR + li] = fmaxf(o6 * innrm, 0.f);
        xT[(kb + 7) * XSTR + li] = fmaxf(o7 * innrm, 0.f);
    }
    __syncthreads();                            // agg done; lsw region free

    const float4* W4 = (const float4*)W;
    float4* Ws4 = (float4*)Ws;
    #pragma unroll
    for (int i = 0; i < 4; ++i) Ws4[tid + 256 * i] = W4[tid + 256 * i];
    __syncthreads();

    int tx = tid & 15, ty = tid >> 4;
    int c0 = tx << 2, r0 = ty << 2;
    float acc[4][4] = {{0.f}};
    #pragma unroll 8
    for (int k = 0; k < DIM; ++k) {
        float4 xv = *(const float4*)(xT + k * XSTR + r0);
        float4 wv = *(const float4*)(Ws + k * DIM + c0);
        acc[0][0] += xv.x * wv.x; acc[0][1] += xv.x * wv.y; acc[0][2] += xv.x * wv.z; acc[0][3] += xv.x * wv.w;
        acc[1][0] += xv.y * wv.x; acc[1][1] += xv.y * wv.y; acc[1][2] += xv.y * wv.z; acc[1][3] += xv.y * wv.w;
        acc[2][0] += xv.z * wv.x; acc[2][1] += xv.z * wv.y; acc[2][2] += xv.z * wv.z; acc[2][3] += xv.z * wv.w;
        acc[3][0] += xv.w * wv.x; acc[3][1] += xv.w * wv.y; acc[3][2] += xv.w * wv.z; acc[3][3] += xv.w * wv.w;
    }

    float4 av = *(const float4*)(a_s + c0);
    float4 dv = *(const float4*)(a_d + c0);
    #pragma unroll
    for (int ri = 0; ri < 4; ++ri) {
        int grow = base + r0 + ri;
        float s1 = acc[ri][0] * av.x + acc[ri][1] * av.y + acc[ri][2] * av.z + acc[ri][3] * av.w;
        float s2 = acc[ri][0] * dv.x + acc[ri][1] * dv.y + acc[ri][2] * dv.z + acc[ri][3] * dv.w;
        #pragma unroll
        for (int d = 1; d <= 8; d <<= 1) { s1 += __shfl_xor(s1, d); s2 += __shfl_xor(s2, d); }
        if (grow < N) {
            uint2 o;
            o.x = bfpack(acc[ri][0], acc[ri][1]);
            o.y = bfpack(acc[ri][2], acc[ri][3]);
            *(uint2*)(hbn + ((size_t)grow << 5) + (tx << 1)) = o;
            if (tx == 0) { asn[grow] = s1; adn[grow] = s2; }
        }
    }
}

// ---------------- per-node softmax-aggregate (final layer, bf16 out) ----------------
#define AGG_NPB 32
#define AGG_CAP 2048
__global__ __launch_bounds__(256) void gat_agg(const unsigned* __restrict__ hb,
                                               const int2* __restrict__ csr_sd,
                                               const float* __restrict__ as_,
                                               const float* __restrict__ ad_,
                                               const int* __restrict__ offs,
                                               const float* __restrict__ bias,
                                               unsigned* __restrict__ outb, int N) {
    __shared__ int soffs[AGG_NPB + 1];
    __shared__ float adl[AGG_NPB];
    __shared__ int2 lsw[AGG_CAP + 4];
    int tid = threadIdx.x;
    int base = blockIdx.x * AGG_NPB;
    if (tid <= AGG_NPB) {
        int n = base + tid;
        soffs[tid] = offs[n < N ? n : N];
    }
    if (tid < AGG_NPB) {
        int n = base + tid;
        adl[tid] = (n < N) ? ad_[n] : 0.f;
    }
    __syncthreads();
    int estart = soffs[0];
    int nE = soffs[AGG_NPB] - estart;
    bool inLds = (nE <= AGG_CAP);
    if (inLds) {
        for (int i = tid; i < nE; i += 256) {
            int2 sd = csr_sd[estart + i];
            float e = as_[sd.x] + adl[sd.y - base];
            e = (e > 0.f) ? e : 0.2f * e;
            lsw[i] = make_int2(sd.x, __builtin_bit_cast(int, expf(e)));
        }
        if (tid < 4) lsw[nE + tid] = make_int2(0, 0);
    }
    __syncthreads();

    int lane = tid & 63, wid = tid >> 6;
    int sub = lane >> 3, fg = lane & 7;          // 8 node-groups/wave, 8 lanes each
    int li = (wid << 3) + sub;                   // local node 0..31
    int node = base + li;
    int ls = soffs[li] - estart;
    int deg = soffs[li + 1] - soffs[li];

    float a0 = 0.f, a1 = 0.f, a2 = 0.f, a3 = 0.f;
    float a4 = 0.f, a5 = 0.f, a6 = 0.f, a7 = 0.f, sw = 0.f;
    if (inLds) {
        for (int eb = 0; eb < deg; eb += 4) {
            int t = ls + eb;
            int2 eA = lsw[t], eB = lsw[t + 1], eC = lsw[t + 2], eD = lsw[t + 3];
            float wA = __builtin_bit_cast(float, eA.y);
            float wB = (eb + 1 < deg) ? __builtin_bit_cast(float, eB.y) : 0.f;
            float wC = (eb + 2 < deg) ? __builtin_bit_cast(float, eC.y) : 0.f;
            float wD = (eb + 3 < deg) ? __builtin_bit_cast(float, eD.y) : 0.f;
            const uint4 hA = *(const uint4*)(hb + ((size_t)eA.x << 5) + (fg << 2));
            const uint4 hB = *(const uint4*)(hb + ((size_t)eB.x << 5) + (fg << 2));
            const uint4 hC = *(const uint4*)(hb + ((size_t)eC.x << 5) + (fg << 2));
            const uint4 hD = *(const uint4*)(hb + ((size_t)eD.x << 5) + (fg << 2));
            sw += wA + wB + wC + wD;
            a0 += wA * bflo(hA.x) + wB * bflo(hB.x) + wC * bflo(hC.x) + wD * bflo(hD.x);
            a1 += wA * bfhi(hA.x) + wB * bfhi(hB.x) + wC * bfhi(hC.x) + wD * bfhi(hD.x);
            a2 += wA * bflo(hA.y) + wB * bflo(hB.y) + wC * bflo(hC.y) + wD * bflo(hD.y);
            a3 += wA * bfhi(hA.y) + wB * bfhi(hB.y) + wC * bfhi(hC.y) + wD * bfhi(hD.y);
            a4 += wA * bflo(hA.z) + wB * bflo(hB.z) + wC * bflo(hC.z) + wD * bflo(hD.z);
            a5 += wA * bfhi(hA.z) + wB * bfhi(hB.z) + wC * bfhi(hC.z) + wD * bfhi(hD.z);
            a6 += wA * bflo(hA.w) + wB * bflo(hB.w) + wC * bflo(hC.w) + wD * bflo(hD.w);
            a7 += wA * bfhi(hA.w) + wB * bfhi(hB.w) + wC * bfhi(hC.w) + wD * bfhi(hD.w);
        }
    } else {
        float adi = (node < N) ? ad_[node] : 0.f;
        for (int eb = 0; eb < deg; eb += 4) {
            int t = estart + ls + eb;
            float wv[4]; int sv[4];
            #pragma unroll
            for (int k = 0; k < 4; ++k) {
                int2 sd = (eb + k < deg) ? csr_sd[t + k] : make_int2(0, 0);
                int s = sd.x; s = s < 0 ? 0 : (s >= N ? N - 1 : s);
                float e = as_[s] + adi;
                e = (e > 0.f) ? e : 0.2f * e;
                wv[k] = (eb + k < deg) ? expf(e) : 0.f;
                sv[k] = s;
            }
            #pragma unroll
            for (int k = 0; k < 4; ++k) {
                const uint4 hv = *(const uint4*)(hb + ((size_t)sv[k] << 5) + (fg << 2));
                sw += wv[k];
                a0 += wv[k] * bflo(hv.x); a1 += wv[k] * bfhi(hv.x);
                a2 += wv[k] * bflo(hv.y); a3 += wv[k] * bfhi(hv.y);
                a4 += wv[k] * bflo(hv.z); a5 += wv[k] * bfhi(hv.z);
                a6 += wv[k] * bflo(hv.w); a7 += wv[k] * bfhi(hv.w);
            }
        }
    }

    float inv = 1.f / (sw + 1e-16f);
    const float4 b0 = *(const float4*)(bias + (fg << 3));
    const float4 b1 = *(const float4*)(bias + (fg << 3) + 4);
    float o0 = a0 * inv + b0.x, o1 = a1 * inv + b0.y, o2 = a2 * inv + b0.z, o3 = a3 * inv + b0.w;
    float o4 = a4 * inv + b1.x, o5 = a5 * inv + b1.y, o6 = a6 * inv + b1.z, o7 = a7 * inv + b1.w;
    float n2 = o0 * o0 + o1 * o1 + o2 * o2 + o3 * o3 + o4 * o4 + o5 * o5 + o6 * o6 + o7 * o7;
    #pragma unroll
    for (int d = 1; d <= 4; d <<= 1) n2 += __shfl_xor(n2, d);   // across the 8 fg lanes
    float innrm = 1.f / fmaxf(sqrtf(n2), 1e-12f);
    if (node < N) {
        uint4 o;
        o.x = bfpack(fmaxf(o0 * innrm, 0.f), fmaxf(o1 * innrm, 0.f));
        o.y = bfpack(fmaxf(o2 * innrm, 0.f), fmaxf(o3 * innrm, 0.f));
        o.z = bfpack(fmaxf(o4 * innrm, 0.f), fmaxf(o5 * innrm, 0.f));
        o.w = bfpack(fmaxf(o6 * innrm, 0.f), fmaxf(o7 * innrm, 0.f));
        *(uint4*)(outb + ((size_t)node << 5) + (fg << 2)) = o;
    }
}

// ---------------- fused global_add_pool + MLP + log_softmax ----------------
__global__ __launch_bounds__(256) void pool_mlp(const unsigned short* __restrict__ hb, const int* __restrict__ gstart,
                                                const float* __restrict__ fc1w, const float* __restrict__ fc1b,
                                                const float* __restrict__ fc2w, const float* __restrict__ fc2b,
                                                float* __restrict__ out) {
    __shared__ float W1[DIM * DIM];
    __shared__ float red[4 * DIM];
    __shared__ float tbuf[DIM];
    __shared__ float obuf[CNUM];
    int tid = threadIdx.x, lane = tid & 63, wv = tid >> 6;
    int gid = blockIdx.x;

    const float4* W4 = (const float4*)fc1w;
    float4* W1s = (float4*)W1;
    #pragma unroll
    for (int i = 0; i < 4; ++i) W1s[tid + 256 * i] = W4[tid + 256 * i];

    int s = gstart[gid], e = gstart[gid + 1];
    float acc = 0.f;
    for (int i = s + wv; i < e; i += 4) acc += bfs(hb[((size_t)i << 6) + lane]);
    red[wv * DIM + lane] = acc;
    __syncthreads();

    if (wv == 0) {
        float g = red[lane] + red[DIM + lane] + red[2 * DIM + lane] + red[3 * DIM + lane];
        float t = fc1b[lane];
        #pragma unroll
        for (int k = 0; k < DIM; ++k) t += __shfl(g, k) * W1[k * DIM + lane];
        t = fmaxf(t, 0.f);
        tbuf[lane] = t;
        float o = 0.f;
        if (lane < CNUM) {
            o = fc2b[lane];
            #pragma unroll
            for (int k = 0; k < DIM; ++k) o += tbuf[k] * fc2w[k * CNUM + lane];
            obuf[lane] = o;
        }
        if (lane < CNUM) {
            float mx = obuf[0];
            #pragma unroll
            for (int k = 1; k < CNUM; ++k) mx = fmaxf(mx, obuf[k]);
            float ssum = 0.f;
            #pragma unroll
            for (int k = 0; k < CNUM; ++k) ssum += expf(obuf[k] - mx);
            out[gid * CNUM + lane] = o - mx - logf(ssum);
        }
    }
}

// ---------------- launch ----------------
static inline size_t align256(size_t x) { return (x + 255) & ~size_t(255); }

extern "C" void kernel_launch(void* const* d_in, const int* in_sizes, int n_in,
                              void* d_out, int out_size, void* d_ws, size_t ws_size,
                              hipStream_t stream) {
    const float* x     = (const float*)d_in[0];
    const int*   ei    = (const int*)d_in[1];
    const int*   batch = (const int*)d_in[2];
    const float* w1  = (const float*)d_in[3];
    const float* as1 = (const float*)d_in[4];
    const float* ad1 = (const float*)d_in[5];
    const float* b1  = (const float*)d_in[6];
    const float* w2  = (const float*)d_in[7];
    const float* as2 = (const float*)d_in[8];
    const float* ad2 = (const float*)d_in[9];
    const float* b2  = (const float*)d_in[10];
    const float* w3  = (const float*)d_in[11];
    const float* as3 = (const float*)d_in[12];
    const float* ad3 = (const float*)d_in[13];
    const float* b3  = (const float*)d_in[14];
    const float* fc1w = (const float*)d_in[15];
    const float* fc1b = (const float*)d_in[16];
    const float* fc2w = (const float*)d_in[17];
    const float* fc2b = (const float*)d_in[18];
    float* out = (float*)d_out;

    int N  = in_sizes[0] / DIM;
    int E  = in_sizes[1] / 2;
    int EP = E + N;
    int nb = (N + 255) / 256;   // scan blocks (<= 256 for N <= 65536)

    // workspace carve (ping-pong h/as/ad buffers for the fused layers)
    char* p = (char*)d_ws;
    unsigned* hbA = (unsigned*)p; p += align256(sizeof(unsigned) * (size_t)N * (DIM / 2));
    unsigned* hbB = (unsigned*)p; p += align256(sizeof(unsigned) * (size_t)N * (DIM / 2));
    unsigned* oAb = (unsigned*)p; p += align256(sizeof(unsigned) * (size_t)N * (DIM / 2));
    float* asA  = (float*)p; p += align256(sizeof(float) * (size_t)N);
    float* adA  = (float*)p; p += align256(sizeof(float) * (size_t)N);
    float* asB  = (float*)p; p += align256(sizeof(float) * (size_t)N);
    float* adB  = (float*)p; p += align256(sizeof(float) * (size_t)N);
    int*   deg  = (int*)p;   p += align256(sizeof(int) * (size_t)N);
    int*   offs = (int*)p;   p += align256(sizeof(int) * (size_t)(N + 1));
    int*   rank = (int*)p;   p += align256(sizeof(int) * (size_t)EP);
    int2*  csr_sd = (int2*)p; p += align256(sizeof(int2) * (size_t)EP);
    int*   part = (int*)p;   p += align256(sizeof(int) * (size_t)nb);
    int*   gst  = (int*)p;   p += align256(sizeof(int) * (size_t)(GNUM + 1));

    int nfb  = (N + FUS_NPB - 1) / FUS_NPB;   // fused agg+mm blocks (64 nodes)
    int nblk = (N + AGG_NPB - 1) / AGG_NPB;   // final gat_agg (32 nodes)
    int nbt = (N + 63) / 64;                  // mm tiles
    int epBlocks = (EP + 255) / 256;

    // CSR build (dst-grouped; layer-invariant)
    hipMemsetAsync(deg, 0, sizeof(int) * (size_t)N, stream);
    deg_rank_kernel<<<epBlocks, 256, 0, stream>>>(ei, E, N, deg, rank);
    scan_misc<<<nb + 1, 256, 0, stream>>>(deg, part, N, nb, batch, N, gst);
    scan_down<<<nb, 256, 0, stream>>>(deg, part, offs, N);

    // layer 1 mm (+ CSR scatter overlapped)
    mm_fill<<<nbt + epBlocks, 256, 0, stream>>>(x, w1, as1, ad1, hbA, asA, adA, N, nbt,
                                                ei, rank, E, offs, csr_sd);
    // fused agg(1)+mm(2), agg(2)+mm(3)
    agg_mm<<<nfb, 256, 0, stream>>>(hbA, csr_sd, asA, adA, offs, b1, w2, as2, ad2,
                                    hbB, asB, adB, N);
    agg_mm<<<nfb, 256, 0, stream>>>(hbB, csr_sd, asB, adB, offs, b2, w3, as3, ad3,
                                    hbA, asA, adA, N);
    // final agg(3) -> bf16 rows for pooling
    gat_agg<<<nblk, 256, 0, stream>>>(hbA, csr_sd, asA, adA, offs, b3, oAb, N);

    // fused pool + head (bf16 input)
    pool_mlp<<<GNUM, 256, 0, stream>>>((const unsigned short*)oAb, gst, fc1w, fc1b, fc2w, fc2b, out);
}